// Round 8
// baseline (258.115 us; speedup 1.0000x reference)
//
#include <hip/hip_runtime.h>
#include <hip/hip_fp16.h>

// GCN 3-layer encoder, aggregate-first form (A_hat commutes with W):
//   per layer: Xs = D^-1/2 (A+I) D^-1/2 X  (gather, fp16 in, fp32 LDS tile)
//              out = act(Xs @ W + b) [* dis, packed fp16 for next layer]
// Layer kernel = r12 shape (best measured: 57.0us for NCB=2): one block = 64
// nodes; phase A gathers 4x16 rows into LDS Xs (16-lane groups, lane owns 4
// features); phase B = 64x64(xNCB) tiled GEMM, W staged to LDS BEFORE the
// gather so its global loads hide under gather latency. (256,4).
// LESSON (r12/r14/r15): layer time is PINNED at 57-59us across tile size,
// W-staging policy, and occupancy 23->49% -> random-line service floor
// (~1.1M random 128B lines/layer). Stop rearranging the layer.
// r16 (this round): attack the CSR build (~85us estimated residual).
// Old bin_scatter wrote pairs at bucket-major GLOBAL positions -> each 128B
// line receives ~30 writes from ~30 blocks across 8 XCDs -> partial-line
// dirty ping-pong through L3 (r8's amplification, relocated). New build:
// chunk-local counting sort -- each block sorts its 4096 edges by bucket
// within its OWN 16KB pairs region (block-local, ~sequential writes) and
// emits locScan[chunk][bucket]; bucket_fill reads per-bucket data as 245
// short runs (read-only). Deletes bin_hist + bucket_prefix (scatter
// re-histograms its chunk in LDS; bucket_tot via global atomics).
// Build: memset(tot) -> build_scatter -> bucket_scan -> bucket_fill.
// LESSON (r3/r4): never take addresses of register data; cap GEMM K unroll
// at 2 (full unroll -> 256 VGPR + scratch spill).
// LESSON (r5/r7/r8): gather is latency/fetch-bound; fp16 staging halves bytes.
// LESSON (r9, FAILED): no wave-level matvec fusion (W wants 64 VGPR).
// LESSON (r10): 16-lanes-own-4-features gather beats butterfly.
// LESSON (r11, NEUTRAL): gather is NOT issue-limited.
// LESSON (r13): never force waves below the register working set (spill
// shows up as WRITE_SIZE delta).
// LESSON (r14): occupancy above ~24 waves/CU buys nothing -- line-bound.
// NOTE: per-XCD L2 reuse for the gather is capped at deg/8 XCDs = 1.25 --
// dim-sliced multi-pass blocking computes to IDENTICAL fill traffic; don't try.

#define NBMAX 512   // max buckets (n <= 131072; src must fit 17 bits for packing)
#define EPB   4096  // edges per chunk (nblkA = ceil(E/EPB) = 245)

// ---------------- chunk-local counting-sort CSR build ----------------

// Scatter: per chunk, histogram (LDS) -> bucket_tot atomics -> local scan ->
// locScan out -> sort chunk's edges by bucket into pairs[chunk region].
// All pairs writes are block-local (own 16KB region) -> no cross-XCD RMW.
__global__ __launch_bounds__(512) void build_scatter(
    const int* __restrict__ src, const int* __restrict__ dst,
    int* __restrict__ bucket_tot, int* __restrict__ locScan,
    int* __restrict__ pairs, int E, int NB) {
  __shared__ int cnt[NBMAX];
  __shared__ int tmp[NBMAX];
  int c = blockIdx.x;
  int t = threadIdx.x;
  int base = c * EPB;
  for (int i = t; i < NB; i += 512) cnt[i] = 0;
  __syncthreads();
  int myS[8], myD[8];
#pragma unroll
  for (int i = 0; i < 8; ++i) {  // stash chunk edges in registers (16 VGPR)
    int e = base + i * 512 + t;
    bool v = e < E;
    myS[i] = v ? src[e] : -1;
    myD[i] = v ? dst[e] : 0;
    if (v) atomicAdd(&cnt[myD[i] >> 8], 1);
  }
  __syncthreads();
  if (t < NB) atomicAdd(&bucket_tot[t], cnt[t]);
  // exclusive scan of cnt over buckets (Hillis-Steele, 512 wide)
  int v = (t < NB) ? cnt[t] : 0;
  tmp[t] = v;
  __syncthreads();
  for (int off = 1; off < 512; off <<= 1) {
    int a = (t >= off) ? tmp[t - off] : 0;
    __syncthreads();
    tmp[t] += a;
    __syncthreads();
  }
  int excl = tmp[t] - v;
  size_t lsBase = (size_t)c * (NB + 1);
  if (t < NB) locScan[lsBase + t] = excl;
  if (t == NB - 1) locScan[lsBase + NB] = tmp[t];  // chunk edge count
  __syncthreads();
  if (t < NB) cnt[t] = excl;  // reuse as cursor
  __syncthreads();
#pragma unroll
  for (int i = 0; i < 8; ++i) {
    if (myS[i] >= 0) {
      int pos = atomicAdd(&cnt[myD[i] >> 8], 1);
      pairs[base + pos] = myS[i] | ((myD[i] & 255) << 17);
    }
  }
}

// Exclusive scan of bucket totals -> bucket_off[0..NB], bucket_off[NB]=E.
__global__ __launch_bounds__(512) void bucket_scan(const int* __restrict__ bucket_tot,
                                                   int* __restrict__ bucket_off, int NB, int E) {
  __shared__ int tmp[NBMAX];
  int t = threadIdx.x;
  int v = (t < NB) ? bucket_tot[t] : 0;
  tmp[t] = v;
  __syncthreads();
  for (int off = 1; off < 512; off <<= 1) {
    int a = (t >= off) ? tmp[t - off] : 0;
    __syncthreads();
    tmp[t] += a;
    __syncthreads();
  }
  if (t < NB) bucket_off[t] = tmp[t] - v;
  if (t == 0) bucket_off[NB] = E;
}

__device__ __forceinline__ unsigned int packh(float a, float b) {
  unsigned int lo = (unsigned int)__half_as_ushort(__float2half_rn(a));
  unsigned int hi = (unsigned int)__half_as_ushort(__float2half_rn(b));
  return lo | (hi << 16);
}

__device__ __forceinline__ void unpack_add(float& x0, float& x1, unsigned int u) {
  x0 += __half2float(__ushort_as_half((unsigned short)(u & 0xffffu)));
  x1 += __half2float(__ushort_as_half((unsigned short)(u >> 16)));
}

// Fill: per bucket, read the bucket's edges as nchunk short runs (locScan),
// histogram -> row_ptr + dis, cursor-scatter csr_src (block-local window),
// then fused prescale of this bucket's 256 rows: xs = fp16(x * dis[row]).
__global__ __launch_bounds__(256) void bucket_fill(const int* __restrict__ pairs,
                                                   const int* __restrict__ locScan,
                                                   const int* __restrict__ bucket_off,
                                                   int* __restrict__ row_ptr,
                                                   int* __restrict__ csr_src,
                                                   float* __restrict__ dis,
                                                   const float* __restrict__ x,
                                                   unsigned short* __restrict__ xs,
                                                   int n, int NB, int nchunk) {
  __shared__ int cnt[256];
  __shared__ int tmp[256];
  __shared__ int cur[256];
  __shared__ float sdis[256];
  int b = blockIdx.x;
  int t = threadIdx.x;
  int node_base = b << 8;
  int ebeg = bucket_off[b];
  int eend = bucket_off[b + 1];
  cnt[t] = 0;
  __syncthreads();
  // pass 1: histogram over this bucket's runs (thread per chunk)
  for (int c = t; c < nchunk; c += 256) {
    int s = locScan[(size_t)c * (NB + 1) + b];
    int e = locScan[(size_t)c * (NB + 1) + b + 1];
    const int* pp = pairs + (size_t)c * EPB;
    for (int i = s; i < e; ++i) atomicAdd(&cnt[(pp[i] >> 17) & 255], 1);
  }
  __syncthreads();
  int v = cnt[t];
  tmp[t] = v;
  __syncthreads();
  for (int off = 1; off < 256; off <<= 1) {
    int a = (t >= off) ? tmp[t - off] : 0;
    __syncthreads();
    tmp[t] += a;
    __syncthreads();
  }
  int excl = tmp[t] - v;
  int node = node_base + t;
  float s = rsqrtf((float)v + 1.0f);  // +1 = self-loop
  sdis[t] = s;
  if (node < n) {
    row_ptr[node] = ebeg + excl;
    dis[node] = s;
  }
  cur[t] = ebeg + excl;
  if (b == NB - 1 && t == 0) row_ptr[n] = eend;
  __syncthreads();
  // pass 2: scatter csr_src within this bucket's contiguous window
  for (int c = t; c < nchunk; c += 256) {
    int sE = locScan[(size_t)c * (NB + 1) + b];
    int eE = locScan[(size_t)c * (NB + 1) + b + 1];
    const int* pp = pairs + (size_t)c * EPB;
    for (int i = sE; i < eE; ++i) {
      int p = pp[i];
      int pos = atomicAdd(&cur[(p >> 17) & 255], 1);
      csr_src[pos] = p & 0x1FFFF;
    }
  }
  // fused prescale: rows [node_base, node_base+rows) -> fp16, scaled by dis
  int rows = n - node_base;
  if (rows > 256) rows = 256;
  for (int i = t; i < rows * 8; i += 256) {  // 8 x (8-feature) chunks per row
    int r = i >> 3;
    float sc = sdis[r];
    const float4* p = (const float4*)(x + ((size_t)(node_base + r) * 64) + (i & 7) * 8);
    float4 f0 = p[0];
    float4 f1 = p[1];
    uint4 u;
    u.x = packh(f0.x * sc, f0.y * sc);
    u.y = packh(f0.z * sc, f0.w * sc);
    u.z = packh(f1.x * sc, f1.y * sc);
    u.w = packh(f1.z * sc, f1.w * sc);
    *(uint4*)(xs + (size_t)(node_base + r) * 64 + (i & 7) * 8) = u;
  }
}

// ---------------- fused layer: gather(64 nodes) -> GEMM 64x(64*NCB) ----------
// r12 shape (best measured). Phase A: 16-lane groups gather node rows (fp16
// in, fp32 acc) into LDS Xs; full-16 chunks unrolled; masked 16-slot tail
// (clamped loads hit the last edge's line -> L1; fp16 0x0000 == +0.0).
// Phase B: 64x64 tile GEMM per column-block; thread owns 4 rows x 4 cols;
// W staged to LDS BEFORE gather (hides under gather latency).

__device__ __forceinline__ void fma4(float4& a, float s, const float4 w) {
  a.x = fmaf(s, w.x, a.x);
  a.y = fmaf(s, w.y, a.y);
  a.z = fmaf(s, w.z, a.z);
  a.w = fmaf(s, w.w, a.w);
}

template <bool RELU, bool SCALE, bool OUTH, int NCB>
__global__ __launch_bounds__(256, 4) void gcn_layer(
    const int* __restrict__ row_ptr, const int* __restrict__ csr_src,
    const unsigned short* __restrict__ in, const float* __restrict__ dis,
    const float* __restrict__ W, const float* __restrict__ Bv,
    float* __restrict__ yF, unsigned short* __restrict__ yH, int n) {
  __shared__ float Xs[64 * 68];
  __shared__ float Ws[64 * 64 * NCB];
  int tid = threadIdx.x;
  int rb = blockIdx.x * 64;

  // W -> LDS first: global loads issue before gather, hide under its latency
  for (int i = tid; i < 64 * 16 * NCB; i += 256) {
    int k = i / (16 * NCB);
    int cq = (i % (16 * NCB)) << 2;
    *(float4*)&Ws[k * (64 * NCB) + cq] = *(const float4*)&W[(size_t)k * (64 * NCB) + cq];
  }

  // ---- Phase A: gather 64 rows (4 iters x 16 groups of 16 lanes) ----
  int l15 = tid & 15;    // feature slice [4*l15, 4*l15+4)
  int gbase = tid & 48;  // group base lane within the wave
  int grp = tid >> 4;    // group id 0..15
  for (int it = 0; it < 4; ++it) {
    int r = it * 16 + grp;           // local row 0..63
    int cl = min(rb + r, n - 1);     // clamped node (dup rows unused; stores guarded)
    int beg = row_ptr[cl];
    int end = row_ptr[cl + 1];

    float a0 = 0.f, a1 = 0.f, a2 = 0.f, a3 = 0.f;
    {  // self-loop
      uint2 q = *(const uint2*)(in + (size_t)cl * 64 + l15 * 4);
      unpack_add(a0, a1, q.x); unpack_add(a2, a3, q.y);
    }
    int k = beg;
    for (; k + 16 <= end; k += 16) {   // full chunks
      int idx = csr_src[k + l15];
#pragma unroll
      for (int rr = 0; rr < 16; rr += 2) {
        int s0 = __shfl(idx, gbase + rr);
        int s1 = __shfl(idx, gbase + rr + 1);
        uint2 q0 = *(const uint2*)(in + (size_t)s0 * 64 + l15 * 4);
        uint2 q1 = *(const uint2*)(in + (size_t)s1 * 64 + l15 * 4);
        unpack_add(a0, a1, q0.x); unpack_add(a2, a3, q0.y);
        unpack_add(a0, a1, q1.x); unpack_add(a2, a3, q1.y);
      }
    }
    int cnt = end - k;                 // 0..15, group-uniform
    if (cnt > 0) {                     // masked 16-slot tail
      int ii = k + l15;
      int last = end - 1;
      ii = (ii < end) ? ii : last;
      int idx = csr_src[ii];
#pragma unroll
      for (int rr = 0; rr < 16; rr += 2) {
        int s0 = __shfl(idx, gbase + rr);
        int s1 = __shfl(idx, gbase + rr + 1);
        uint2 q0 = *(const uint2*)(in + (size_t)s0 * 64 + l15 * 4);
        uint2 q1 = *(const uint2*)(in + (size_t)s1 * 64 + l15 * 4);
        q0.x = (rr < cnt) ? q0.x : 0u;      // fp16 0x0000 == +0.0
        q0.y = (rr < cnt) ? q0.y : 0u;
        q1.x = (rr + 1 < cnt) ? q1.x : 0u;
        q1.y = (rr + 1 < cnt) ? q1.y : 0u;
        unpack_add(a0, a1, q0.x); unpack_add(a2, a3, q0.y);
        unpack_add(a0, a1, q1.x); unpack_add(a2, a3, q1.y);
      }
    }
    float sc = dis[cl];
    *(float4*)&Xs[r * 68 + l15 * 4] =
        make_float4(a0 * sc, a1 * sc, a2 * sc, a3 * sc);
  }
  __syncthreads();

  // ---- Phase B: tiled GEMM from LDS ----
  int r0 = (tid >> 4) << 2;
  int c0 = (tid & 15) << 2;
  int gr0 = rb + r0;

#pragma unroll
  for (int cb = 0; cb < NCB; ++cb) {
    float4 a0 = make_float4(0.f, 0.f, 0.f, 0.f);
    float4 a1 = a0, a2 = a0, a3 = a0;

#pragma unroll 2
    for (int kc = 0; kc < 64; kc += 4) {
      float4 x0 = *(const float4*)&Xs[(r0 + 0) * 68 + kc];
      float4 x1 = *(const float4*)&Xs[(r0 + 1) * 68 + kc];
      float4 x2 = *(const float4*)&Xs[(r0 + 2) * 68 + kc];
      float4 x3 = *(const float4*)&Xs[(r0 + 3) * 68 + kc];
      const float* wp = &Ws[(size_t)kc * (64 * NCB) + cb * 64 + c0];
      float4 w0 = *(const float4*)(wp + 0 * (64 * NCB));
      float4 w1 = *(const float4*)(wp + 1 * (64 * NCB));
      float4 w2 = *(const float4*)(wp + 2 * (64 * NCB));
      float4 w3 = *(const float4*)(wp + 3 * (64 * NCB));
      fma4(a0, x0.x, w0); fma4(a0, x0.y, w1); fma4(a0, x0.z, w2); fma4(a0, x0.w, w3);
      fma4(a1, x1.x, w0); fma4(a1, x1.y, w1); fma4(a1, x1.z, w2); fma4(a1, x1.w, w3);
      fma4(a2, x2.x, w0); fma4(a2, x2.y, w1); fma4(a2, x2.z, w2); fma4(a2, x2.w, w3);
      fma4(a3, x3.x, w0); fma4(a3, x3.y, w1); fma4(a3, x3.z, w2); fma4(a3, x3.w, w3);
    }

    float4 bb = *(const float4*)&Bv[cb * 64 + c0];
#pragma unroll
    for (int ri = 0; ri < 4; ++ri) {
      int gr = gr0 + ri;
      if (gr >= n) break;
      float4 v = (ri == 0) ? a0 : (ri == 1) ? a1 : (ri == 2) ? a2 : a3;
      v.x += bb.x; v.y += bb.y; v.z += bb.z; v.w += bb.w;
      if (RELU) {
        v.x = fmaxf(v.x, 0.f); v.y = fmaxf(v.y, 0.f);
        v.z = fmaxf(v.z, 0.f); v.w = fmaxf(v.w, 0.f);
      }
      if (SCALE) {
        float s = dis[gr];
        v.x *= s; v.y *= s; v.z *= s; v.w *= s;
      }
      if (OUTH) {
        uint2 u;
        u.x = packh(v.x, v.y);
        u.y = packh(v.z, v.w);
        *(uint2*)(yH + (size_t)gr * 64 + c0) = u;
      } else {
        *(float4*)&yF[(size_t)gr * (64 * NCB) + cb * 64 + c0] = v;
      }
    }
  }
}

// ---------------- launch ----------------

extern "C" void kernel_launch(void* const* d_in, const int* in_sizes, int n_in,
                              void* d_out, int out_size, void* d_ws, size_t ws_size,
                              hipStream_t stream) {
  const float* x  = (const float*)d_in[0];
  const float* W1 = (const float*)d_in[1];
  const float* b1 = (const float*)d_in[2];
  const float* W2 = (const float*)d_in[3];
  const float* b2 = (const float*)d_in[4];
  const float* W3 = (const float*)d_in[5];
  const float* b3 = (const float*)d_in[6];
  const int*   ei = (const int*)d_in[7];

  const int n = in_sizes[0] / 64;   // 100000
  const int E = in_sizes[7] / 2;    // 1000000
  const int* src = ei;
  const int* dst = ei + E;

  const int NB    = (n + 255) >> 8;         // buckets (256 nodes each): 391
  const int nblkA = (E + EPB - 1) / EPB;    // chunks: 245

  // Workspace: dis[n] f32 | bufA[n*64] fp16 | bufB[n*64] fp16 | row_ptr[n+2] |
  //            csr_src[E] | pairs[E] | locScan[nblkA*(NB+1)] | tot[NB] | off[NB+1]
  float* dis = (float*)d_ws;
  unsigned short* bufA = (unsigned short*)(dis + n);
  unsigned short* bufB = bufA + (size_t)n * 64;
  int* row_ptr = (int*)(bufB + (size_t)n * 64);
  int* csr_src = row_ptr + (n + 2);
  int* pairs   = csr_src + E;
  int* locScan = pairs + E;
  int* bucket_tot = locScan + (size_t)nblkA * (NB + 1);
  int* bucket_off = bucket_tot + NB;
  float* out = (float*)d_out;

  dim3 blk(256);
  int gL = (n + 63) / 64;         // fused layer: 64 nodes per block

  // --- chunk-local counting-sort CSR build (+ dis, + fused prescale) ---
  hipMemsetAsync(bucket_tot, 0, (size_t)NB * sizeof(int), stream);
  build_scatter<<<nblkA, 512, 0, stream>>>(src, dst, bucket_tot, locScan, pairs, E, NB);
  bucket_scan<<<1, 512, 0, stream>>>(bucket_tot, bucket_off, NB, E);
  bucket_fill<<<NB, blk, 0, stream>>>(pairs, locScan, bucket_off, row_ptr, csr_src,
                                      dis, x, bufA, n, NB, nblkA);

  // --- Layer 1: fused gather+GEMM (relu, scale, fp16 out), bufA -> bufB ---
  gcn_layer<true, true, true, 1><<<gL, blk, 0, stream>>>(
      row_ptr, csr_src, bufA, dis, W1, b1, nullptr, bufB, n);

  // --- Layer 2: bufB -> bufA ---
  gcn_layer<true, true, true, 1><<<gL, blk, 0, stream>>>(
      row_ptr, csr_src, bufB, dis, W2, b2, nullptr, bufA, n);

  // --- Layer 3: bufA -> out (fp32, 128 cols) ---
  gcn_layer<false, false, false, 2><<<gL, blk, 0, stream>>>(
      row_ptr, csr_src, bufA, dis, W3, b3, out, nullptr, n);
}